// Round 10
// baseline (279.968 us; speedup 1.0000x reference)
//
#include <hip/hip_runtime.h>

typedef unsigned short u16;
typedef unsigned int   u32;
typedef float  f32x4  __attribute__((ext_vector_type(4)));
typedef __bf16 bf16x8 __attribute__((ext_vector_type(8)));
typedef u16    u16x8  __attribute__((ext_vector_type(8)));
typedef u32    u32x4  __attribute__((ext_vector_type(4)));
typedef u32    u32x2  __attribute__((ext_vector_type(2)));

#define DEVINL static __device__ __forceinline__

constexpr int CC = 256, DD = 32, NN = 4096;
constexpr float L2E = 1.4426950408889634f;

DEVINL f32x4 mfma16(u16x8 a, u16x8 b, f32x4 c) {
  return __builtin_amdgcn_mfma_f32_16x16x32_bf16(
      __builtin_bit_cast(bf16x8, a), __builtin_bit_cast(bf16x8, b), c, 0, 0, 0);
}

DEVINL u32 pk_bf16(float lo, float hi) {
  u32 r;
  asm("v_cvt_pk_bf16_f32 %0, %1, %2" : "=v"(r) : "v"(lo), "v"(hi));
  return r;
}

DEVINL float exp2fast(float x) { return __builtin_amdgcn_exp2f(x); }

DEVINL float lo16(u32 v) { u32 b = v << 16;          return __builtin_bit_cast(float, b); }
DEVINL float hi16(u32 v) { u32 b = v & 0xffff0000u;  return __builtin_bit_cast(float, b); }

// ---------------------------------------------------------------------------
// Kernel 1: projections as MFMA GEMM — self-contained (round-5 verified,
// byte-identical).
// ---------------------------------------------------------------------------
__global__ __launch_bounds__(256, 2) void proj_kernel(
    const float* __restrict__ in,
    const float* __restrict__ wq, const float* __restrict__ wk,
    const float* __restrict__ wv,
    const float* __restrict__ bq, const float* __restrict__ bk,
    const float* __restrict__ bv,
    u16* __restrict__ qT, u16* __restrict__ kT, u16* __restrict__ vbf) {
  __shared__ u16 xT[64 * 264];   // [n][c] bf16, rows 528B (512 data + 16 pad)
  const int t  = threadIdx.x;
  const int b  = blockIdx.x & 7;
  const int n0 = (blockIdx.x >> 3) * 64;

  {  // stage x tile -> transposed bf16 LDS
    const int n = t & 63;
    const int cg0 = t >> 6;
    const float* src = in + (size_t)b * 256 * NN + n0 + n;
#pragma unroll
    for (int pass = 0; pass < 8; ++pass) {
      const int cg = cg0 + pass * 4;
      float x[8];
#pragma unroll
      for (int j = 0; j < 8; ++j) x[j] = src[(size_t)(cg * 8 + j) * NN];
      u32x4 p;
      p.x = pk_bf16(x[0], x[1]); p.y = pk_bf16(x[2], x[3]);
      p.z = pk_bf16(x[4], x[5]); p.w = pk_bf16(x[6], x[7]);
      *(u32x4*)(&xT[n * 264 + cg * 8]) = p;
    }
  }
  __syncthreads();

  const int lane = t & 63, w = t >> 6;
  const int r = lane & 15, g = lane >> 4;
  const int o0 = w * 80;

  const float* wsrc[5];
#pragma unroll
  for (int ot = 0; ot < 5; ++ot) {
    const int o = o0 + ot * 16 + r;
    wsrc[ot] = (o < 256) ? wv + (size_t)o * 256
             : (o < 288) ? wq + (size_t)(o - 256) * 256
                         : wk + (size_t)(o - 288) * 256;
  }

  f32x4 acc[5][4];
#pragma unroll
  for (int ot = 0; ot < 5; ++ot)
#pragma unroll
    for (int nt = 0; nt < 4; ++nt) acc[ot][nt] = f32x4{0.f, 0.f, 0.f, 0.f};

#pragma unroll
  for (int k = 0; k < 8; ++k) {
    u16x8 a[5], bfr[4];
#pragma unroll
    for (int ot = 0; ot < 5; ++ot) {
      const f32x4 w0 = *(const f32x4*)(wsrc[ot] + k * 32 + 8 * g);
      const f32x4 w1 = *(const f32x4*)(wsrc[ot] + k * 32 + 8 * g + 4);
      const u32x4 pw = {pk_bf16(w0.x, w0.y), pk_bf16(w0.z, w0.w),
                        pk_bf16(w1.x, w1.y), pk_bf16(w1.z, w1.w)};
      a[ot] = __builtin_bit_cast(u16x8, pw);
    }
#pragma unroll
    for (int nt = 0; nt < 4; ++nt)
      bfr[nt] = *(const u16x8*)(&xT[(r + 16 * nt) * 264 + k * 32 + g * 8]);
#pragma unroll
    for (int ot = 0; ot < 5; ++ot)
#pragma unroll
      for (int nt = 0; nt < 4; ++nt)
        acc[ot][nt] = mfma16(a[ot], bfr[nt], acc[ot][nt]);
  }

#pragma unroll
  for (int ot = 0; ot < 5; ++ot) {
    const int ob = o0 + ot * 16;
    if (ob < 256) {
      const f32x4 bs = *(const f32x4*)(bv + ob + 4 * g);
#pragma unroll
      for (int nt = 0; nt < 4; ++nt)
#pragma unroll
        for (int j = 0; j < 4; ++j) {
          const float vvv = acc[ot][nt][j] + bs[j];
          vbf[(size_t)(b * 256 + ob + 4 * g + j) * NN + n0 + r + 16 * nt] =
              (u16)(pk_bf16(vvv, 0.f) & 0xffffu);
        }
    } else {
      u16* dst;
      const float* bsrc;
      if (ob < 288) { dst = qT; bsrc = bq + (ob - 256); }
      else          { dst = kT; bsrc = bk + (ob - 288); }
      const f32x4 bs = *(const f32x4*)(bsrc + 4 * g);
      const int d0 = ((ob - 256) & 31) + 4 * g;
#pragma unroll
      for (int nt = 0; nt < 4; ++nt) {
        u32x2 pq;
        pq.x = pk_bf16(acc[ot][nt][0] + bs[0], acc[ot][nt][1] + bs[1]);
        pq.y = pk_bf16(acc[ot][nt][2] + bs[2], acc[ot][nt][3] + bs[3]);
        *(u32x2*)(dst + (size_t)(b * NN + n0 + r + 16 * nt) * 32 + d0) = pq;
      }
    }
  }
}

// ---------------------------------------------------------------------------
// Kernel 2: per-column softmax statistics (verified, byte-identical).
// ---------------------------------------------------------------------------
__global__ __launch_bounds__(256) void rowstat_kernel(
    const u16* __restrict__ qT, const u16* __restrict__ kT,
    float* __restrict__ Mx, float* __restrict__ invL) {
  const int lane = threadIdx.x & 63;
  const int wave = threadIdx.x >> 6;
  const int strip = blockIdx.x * 4 + wave;
  const int b  = strip >> 8;
  const int m0 = (strip & 255) * 16;
  const int r = lane & 15, g = lane >> 4;

  const u16x8 kB = *(const u16x8*)(kT + ((size_t)(b * NN + m0 + r)) * 32 + 8 * g);
  const u16* qbase = qT + ((size_t)(b * NN + r)) * 32 + 8 * g;

  float vmax = -3.0e38f, vsum = 0.f;
  for (int it = 0; it < 256; ++it) {
    const u16x8 qA = *(const u16x8*)(qbase + (size_t)it * 16 * 32);
    f32x4 s = mfma16(qA, kB, f32x4{0.f, 0.f, 0.f, 0.f});
    const float sm = fmaxf(fmaxf(s.x, s.y), fmaxf(s.z, s.w));
    const float nm = fmaxf(vmax, sm);
    vsum = vsum * exp2fast((vmax - nm) * L2E)
         + exp2fast((s.x - nm) * L2E) + exp2fast((s.y - nm) * L2E)
         + exp2fast((s.z - nm) * L2E) + exp2fast((s.w - nm) * L2E);
    vmax = nm;
  }
#pragma unroll
  for (int off = 16; off < 64; off <<= 1) {
    const float om = __shfl_xor(vmax, off);
    const float os = __shfl_xor(vsum, off);
    const float nm = fmaxf(vmax, om);
    vsum = vsum * exp2fast((vmax - nm) * L2E) + os * exp2fast((om - nm) * L2E);
    vmax = nm;
  }
  if (lane < 16) {
    Mx[b * NN + m0 + lane]   = vmax;
    invL[b * NN + m0 + lane] = 1.0f / vsum;
  }
}

// ---------------------------------------------------------------------------
// Kernel 3a: attention — ROUND-5 VERBATIM (verified passing, absmax 0.03125).
// Used as fallback when ws_size cannot hold the partial buffers.
// ---------------------------------------------------------------------------
__global__ __launch_bounds__(512, 2) void attn_kernel(
    const u16* __restrict__ qT, const u16* __restrict__ kT, const u16* __restrict__ vv,
    const float* __restrict__ Mx, const float* __restrict__ invL,
    const float* __restrict__ inp, const float* __restrict__ gptr,
    float* __restrict__ out) {
  __shared__ u32 q_lds[32 * 20];   // rows of 80B (16 data dwords + pad)
  __shared__ u32 v_lds[32 * 20];

  const int tid  = threadIdx.x;
  const int lane = tid & 63;
  const int wave = tid >> 6;                 // 0..7
  const int r = lane & 15, g = lane >> 4;

  const int bi   = blockIdx.x >> 5;          // 8 batches
  const int rest = blockIdx.x & 31;
  const int cs   = rest >> 2;                // 0..7  c-strip
  const int mg   = rest & 3;                 // 0..3  m-group
  const int m0   = (mg * 8 + wave) * 128;
  const int c0   = cs * 32;
  const float gamma = gptr[0];

  u16x8 kB[8];
#pragma unroll
  for (int t = 0; t < 8; ++t)
    kB[t] = *(const u16x8*)(kT + ((size_t)(bi * NN + m0 + t * 16 + r)) * DD + 8 * g);
  float msc[8];
#pragma unroll
  for (int t = 0; t < 8; ++t) msc[t] = Mx[bi * NN + m0 + t * 16 + r] * L2E;

  f32x4 acc[2][8];
#pragma unroll
  for (int cb = 0; cb < 2; ++cb)
#pragma unroll
    for (int t = 0; t < 8; ++t) acc[cb][t] = f32x4{0.f, 0.f, 0.f, 0.f};

  const int srow = tid >> 4;   // 0..31
  const int sdw  = tid & 15;   // dword within row
  const u32* qsrc = (const u32*)(qT + ((size_t)(bi * NN + srow)) * DD) + sdw;
  const u32* vsrc = (const u32*)(vv + ((size_t)(bi * CC + c0 + srow)) * NN) + sdw;
  u32* qdst = q_lds + srow * 20 + sdw;
  u32* vdst = v_lds + srow * 20 + sdw;

  qdst[0] = qsrc[0];
  vdst[0] = vsrc[0];

  for (int i0 = 0; i0 < NN; i0 += 32) {
    __syncthreads();                          // staged tile visible
    const bool more = (i0 + 32) < NN;
    u32 nq = 0, nv = 0;
    if (more) {
      nq = qsrc[(size_t)(i0 + 32) * (DD / 2)];
      nv = vsrc[(i0 + 32) >> 1];
    }

    const u16x8 qA0 = __builtin_bit_cast(u16x8, *(const u32x4*)(q_lds + r * 20 + 4 * g));
    const u16x8 qA1 = __builtin_bit_cast(u16x8, *(const u32x4*)(q_lds + (16 + r) * 20 + 4 * g));
    const u32x2 vl0 = *(const u32x2*)(v_lds + r * 20 + 2 * g);
    const u32x2 vh0 = *(const u32x2*)(v_lds + r * 20 + 2 * g + 8);
    const u32x2 vl1 = *(const u32x2*)(v_lds + (16 + r) * 20 + 2 * g);
    const u32x2 vh1 = *(const u32x2*)(v_lds + (16 + r) * 20 + 2 * g + 8);
    const u16x8 vA0 = __builtin_bit_cast(u16x8, u32x4{vl0.x, vl0.y, vh0.x, vh0.y});
    const u16x8 vA1 = __builtin_bit_cast(u16x8, u32x4{vl1.x, vl1.y, vh1.x, vh1.y});

#pragma unroll
    for (int t = 0; t < 8; ++t) {
      const f32x4 s0 = mfma16(qA0, kB[t], f32x4{0.f, 0.f, 0.f, 0.f});
      const f32x4 s1 = mfma16(qA1, kB[t], f32x4{0.f, 0.f, 0.f, 0.f});
      const float p0 = exp2fast(fmaf(s0.x, L2E, -msc[t]));
      const float p1 = exp2fast(fmaf(s0.y, L2E, -msc[t]));
      const float p2 = exp2fast(fmaf(s0.z, L2E, -msc[t]));
      const float p3 = exp2fast(fmaf(s0.w, L2E, -msc[t]));
      const float p4 = exp2fast(fmaf(s1.x, L2E, -msc[t]));
      const float p5 = exp2fast(fmaf(s1.y, L2E, -msc[t]));
      const float p6 = exp2fast(fmaf(s1.z, L2E, -msc[t]));
      const float p7 = exp2fast(fmaf(s1.w, L2E, -msc[t]));
      const u32x4 pb = {pk_bf16(p0, p1), pk_bf16(p2, p3), pk_bf16(p4, p5), pk_bf16(p6, p7)};
      const u16x8 PB = __builtin_bit_cast(u16x8, pb);
      acc[0][t] = mfma16(vA0, PB, acc[0][t]);
      acc[1][t] = mfma16(vA1, PB, acc[1][t]);
    }
    __syncthreads();                          // all reads done before overwrite
    if (more) { qdst[0] = nq; vdst[0] = nv; }
  }

#pragma unroll
  for (int t = 0; t < 8; ++t) {
    const float il = invL[bi * NN + m0 + t * 16 + r] * gamma;
#pragma unroll
    for (int cb = 0; cb < 2; ++cb) {
#pragma unroll
      for (int rr = 0; rr < 4; ++rr) {
        const int c = c0 + cb * 16 + g * 4 + rr;
        const size_t idx = ((size_t)(bi * CC + c)) * NN + m0 + t * 16 + r;
        out[idx] = acc[cb][t][rr] * il + inp[idx];
      }
    }
  }
}

// ---------------------------------------------------------------------------
// Kernel 3b: attention, i-range split.  IDENTICAL to attn_kernel (r5) except:
// grid 512 = 2 i-halves x 256; bindex = blockIdx&255 decodes exactly as r5;
// half h loops i in [2048h, 2048h+2048); epilogue writes gamma*invL*O_h as
// bf16 partials to pout[h] instead of out.  Wave tile, t<8 loop, kB[8],
// staging expressions, LDS geometry: all r5-verbatim.  2 blocks/CU resident.
// ---------------------------------------------------------------------------
__global__ __launch_bounds__(512, 2) void attn_part_kernel(
    const u16* __restrict__ qT, const u16* __restrict__ kT, const u16* __restrict__ vv,
    const float* __restrict__ Mx, const float* __restrict__ invL,
    const float* __restrict__ gptr, u16* __restrict__ pout) {
  __shared__ u32 q_lds[32 * 20];
  __shared__ u32 v_lds[32 * 20];

  const int tid  = threadIdx.x;
  const int lane = tid & 63;
  const int wave = tid >> 6;                 // 0..7
  const int r = lane & 15, g = lane >> 4;

  const int half   = blockIdx.x >> 8;        // 0,1: i-range half
  const int bindex = blockIdx.x & 255;       // decodes exactly as r5
  const int ibase  = half << 11;             // 0 or 2048

  const int bi   = bindex >> 5;              // 8 batches
  const int rest = bindex & 31;
  const int cs   = rest >> 2;                // 0..7  c-strip
  const int mg   = rest & 3;                 // 0..3  m-group
  const int m0   = (mg * 8 + wave) * 128;
  const int c0   = cs * 32;
  const float gamma = gptr[0];

  u16x8 kB[8];
#pragma unroll
  for (int t = 0; t < 8; ++t)
    kB[t] = *(const u16x8*)(kT + ((size_t)(bi * NN + m0 + t * 16 + r)) * DD + 8 * g);
  float msc[8];
#pragma unroll
  for (int t = 0; t < 8; ++t) msc[t] = Mx[bi * NN + m0 + t * 16 + r] * L2E;

  f32x4 acc[2][8];
#pragma unroll
  for (int cb = 0; cb < 2; ++cb)
#pragma unroll
    for (int t = 0; t < 8; ++t) acc[cb][t] = f32x4{0.f, 0.f, 0.f, 0.f};

  const int srow = tid >> 4;   // 0..31
  const int sdw  = tid & 15;   // dword within row
  const u32* qsrc = (const u32*)(qT + ((size_t)(bi * NN + srow)) * DD) + sdw;
  const u32* vsrc = (const u32*)(vv + ((size_t)(bi * CC + c0 + srow)) * NN) + sdw;
  u32* qdst = q_lds + srow * 20 + sdw;
  u32* vdst = v_lds + srow * 20 + sdw;

  qdst[0] = qsrc[(size_t)ibase * (DD / 2)];  // stage first tile of this half
  vdst[0] = vsrc[ibase >> 1];

  for (int i0 = ibase; i0 < ibase + 2048; i0 += 32) {
    __syncthreads();                          // staged tile visible
    const bool more = (i0 + 32) < (ibase + 2048);
    u32 nq = 0, nv = 0;
    if (more) {
      nq = qsrc[(size_t)(i0 + 32) * (DD / 2)];
      nv = vsrc[(i0 + 32) >> 1];
    }

    const u16x8 qA0 = __builtin_bit_cast(u16x8, *(const u32x4*)(q_lds + r * 20 + 4 * g));
    const u16x8 qA1 = __builtin_bit_cast(u16x8, *(const u32x4*)(q_lds + (16 + r) * 20 + 4 * g));
    const u32x2 vl0 = *(const u32x2*)(v_lds + r * 20 + 2 * g);
    const u32x2 vh0 = *(const u32x2*)(v_lds + r * 20 + 2 * g + 8);
    const u32x2 vl1 = *(const u32x2*)(v_lds + (16 + r) * 20 + 2 * g);
    const u32x2 vh1 = *(const u32x2*)(v_lds + (16 + r) * 20 + 2 * g + 8);
    const u16x8 vA0 = __builtin_bit_cast(u16x8, u32x4{vl0.x, vl0.y, vh0.x, vh0.y});
    const u16x8 vA1 = __builtin_bit_cast(u16x8, u32x4{vl1.x, vl1.y, vh1.x, vh1.y});

#pragma unroll
    for (int t = 0; t < 8; ++t) {
      const f32x4 s0 = mfma16(qA0, kB[t], f32x4{0.f, 0.f, 0.f, 0.f});
      const f32x4 s1 = mfma16(qA1, kB[t], f32x4{0.f, 0.f, 0.f, 0.f});
      const float p0 = exp2fast(fmaf(s0.x, L2E, -msc[t]));
      const float p1 = exp2fast(fmaf(s0.y, L2E, -msc[t]));
      const float p2 = exp2fast(fmaf(s0.z, L2E, -msc[t]));
      const float p3 = exp2fast(fmaf(s0.w, L2E, -msc[t]));
      const float p4 = exp2fast(fmaf(s1.x, L2E, -msc[t]));
      const float p5 = exp2fast(fmaf(s1.y, L2E, -msc[t]));
      const float p6 = exp2fast(fmaf(s1.z, L2E, -msc[t]));
      const float p7 = exp2fast(fmaf(s1.w, L2E, -msc[t]));
      const u32x4 pb = {pk_bf16(p0, p1), pk_bf16(p2, p3), pk_bf16(p4, p5), pk_bf16(p6, p7)};
      const u16x8 PB = __builtin_bit_cast(u16x8, pb);
      acc[0][t] = mfma16(vA0, PB, acc[0][t]);
      acc[1][t] = mfma16(vA1, PB, acc[1][t]);
    }
    __syncthreads();                          // all reads done before overwrite
    if (more) { qdst[0] = nq; vdst[0] = nv; }
  }

  // epilogue: partial = gamma * invL * O_half, stored bf16
  u16* pd = pout + (size_t)half * (8UL * 256 * 4096);
#pragma unroll
  for (int t = 0; t < 8; ++t) {
    const float il = invL[bi * NN + m0 + t * 16 + r] * gamma;
#pragma unroll
    for (int cb = 0; cb < 2; ++cb) {
#pragma unroll
      for (int rr = 0; rr < 4; ++rr) {
        const int c = c0 + cb * 16 + g * 4 + rr;
        const size_t idx = ((size_t)(bi * CC + c)) * NN + m0 + t * 16 + r;
        pd[idx] = (u16)(pk_bf16(acc[cb][t][rr] * il, 0.f) & 0xffffu);
      }
    }
  }
}

// ---------------------------------------------------------------------------
// Kernel 4: combine — out = p0 + p1 + inp (memory-bound, float4/u32x2).
// ---------------------------------------------------------------------------
__global__ __launch_bounds__(256) void combine_kernel(
    const u16* __restrict__ p, const float* __restrict__ inp,
    float* __restrict__ out) {
  const size_t HALF = 8UL * 256 * 4096;      // 8,388,608 elements
  const size_t stride = (size_t)gridDim.x * 256 * 4;
  for (size_t i = ((size_t)blockIdx.x * 256 + threadIdx.x) * 4; i < HALF; i += stride) {
    const u32x2 a = *(const u32x2*)(p + i);
    const u32x2 b = *(const u32x2*)(p + HALF + i);
    const f32x4 x = *(const f32x4*)(inp + i);
    f32x4 o;
    o.x = x.x + lo16(a.x) + lo16(b.x);
    o.y = x.y + hi16(a.x) + hi16(b.x);
    o.z = x.z + lo16(a.y) + lo16(b.y);
    o.w = x.w + hi16(a.y) + hi16(b.y);
    *(f32x4*)(out + i) = o;
  }
}

// ---------------------------------------------------------------------------
// d_ws layout:
//   [0,2MB) qT | [2,4MB) kT | [4,20MB) vbf | [20MB,+128KB) Mx | [+,+256KB) iL
//   [20.25MB, +33.6MB) bf16 partials (only if ws_size permits; else fallback
//   to the r5 single-kernel attn — deterministic branch on ws_size).
// ---------------------------------------------------------------------------
extern "C" void kernel_launch(void* const* d_in, const int* in_sizes, int n_in,
                              void* d_out, int out_size, void* d_ws, size_t ws_size,
                              hipStream_t stream) {
  const float* in  = (const float*)d_in[0];
  const float* wq  = (const float*)d_in[1];
  const float* bq  = (const float*)d_in[2];
  const float* wk  = (const float*)d_in[3];
  const float* bk  = (const float*)d_in[4];
  const float* wv  = (const float*)d_in[5];
  const float* bv  = (const float*)d_in[6];
  const float* gam = (const float*)d_in[7];
  float* out = (float*)d_out;

  char* ws = (char*)d_ws;
  u16* qT   = (u16*)(ws);
  u16* kT   = (u16*)(ws + (2u << 20));
  u16* vbf  = (u16*)(ws + (4u << 20));
  float* Mx = (float*)(ws + (20u << 20));
  float* iL = (float*)(ws + (20u << 20) + (1u << 17));
  u16* pout = (u16*)(ws + (20u << 20) + (1u << 18));

  const size_t need = (20u << 20) + (1u << 18) + 2 * (8UL * 256 * 4096) * 2;

  proj_kernel<<<512, 256, 0, stream>>>(in, wq, wk, wv, bq, bk, bv, qT, kT, vbf);
  rowstat_kernel<<<512, 256, 0, stream>>>(qT, kT, Mx, iL);
  if (ws_size >= need) {
    attn_part_kernel<<<512, 512, 0, stream>>>(qT, kT, vbf, Mx, iL, gam, pout);
    combine_kernel<<<2048, 256, 0, stream>>>(pout, in, out);
  } else {
    attn_kernel<<<256, 512, 0, stream>>>(qT, kT, vbf, Mx, iL, in, gam, out);
  }
}

// Round 11
// 207.748 us; speedup vs baseline: 1.3476x; 1.3476x over previous
//
#include <hip/hip_runtime.h>

typedef unsigned short u16;
typedef unsigned int   u32;
typedef float  f32x4  __attribute__((ext_vector_type(4)));
typedef __bf16 bf16x8 __attribute__((ext_vector_type(8)));
typedef u16    u16x8  __attribute__((ext_vector_type(8)));
typedef u32    u32x4  __attribute__((ext_vector_type(4)));
typedef u32    u32x2  __attribute__((ext_vector_type(2)));

#define DEVINL static __device__ __forceinline__

constexpr int CC = 256, DD = 32, NN = 4096;
constexpr float L2E = 1.4426950408889634f;

DEVINL f32x4 mfma16(u16x8 a, u16x8 b, f32x4 c) {
  return __builtin_amdgcn_mfma_f32_16x16x32_bf16(
      __builtin_bit_cast(bf16x8, a), __builtin_bit_cast(bf16x8, b), c, 0, 0, 0);
}

DEVINL u32 pk_bf16(float lo, float hi) {
  u32 r;
  asm("v_cvt_pk_bf16_f32 %0, %1, %2" : "=v"(r) : "v"(lo), "v"(hi));
  return r;
}

DEVINL float exp2fast(float x) { return __builtin_amdgcn_exp2f(x); }

DEVINL float lo16(u32 v) { u32 b = v << 16;          return __builtin_bit_cast(float, b); }
DEVINL float hi16(u32 v) { u32 b = v & 0xffff0000u;  return __builtin_bit_cast(float, b); }

// ---------------------------------------------------------------------------
// Kernel 1: projections as MFMA GEMM — self-contained (round-5 verified,
// byte-identical).
// ---------------------------------------------------------------------------
__global__ __launch_bounds__(256, 2) void proj_kernel(
    const float* __restrict__ in,
    const float* __restrict__ wq, const float* __restrict__ wk,
    const float* __restrict__ wv,
    const float* __restrict__ bq, const float* __restrict__ bk,
    const float* __restrict__ bv,
    u16* __restrict__ qT, u16* __restrict__ kT, u16* __restrict__ vbf) {
  __shared__ u16 xT[64 * 264];   // [n][c] bf16, rows 528B (512 data + 16 pad)
  const int t  = threadIdx.x;
  const int b  = blockIdx.x & 7;
  const int n0 = (blockIdx.x >> 3) * 64;

  {  // stage x tile -> transposed bf16 LDS
    const int n = t & 63;
    const int cg0 = t >> 6;
    const float* src = in + (size_t)b * 256 * NN + n0 + n;
#pragma unroll
    for (int pass = 0; pass < 8; ++pass) {
      const int cg = cg0 + pass * 4;
      float x[8];
#pragma unroll
      for (int j = 0; j < 8; ++j) x[j] = src[(size_t)(cg * 8 + j) * NN];
      u32x4 p;
      p.x = pk_bf16(x[0], x[1]); p.y = pk_bf16(x[2], x[3]);
      p.z = pk_bf16(x[4], x[5]); p.w = pk_bf16(x[6], x[7]);
      *(u32x4*)(&xT[n * 264 + cg * 8]) = p;
    }
  }
  __syncthreads();

  const int lane = t & 63, w = t >> 6;
  const int r = lane & 15, g = lane >> 4;
  const int o0 = w * 80;

  const float* wsrc[5];
#pragma unroll
  for (int ot = 0; ot < 5; ++ot) {
    const int o = o0 + ot * 16 + r;
    wsrc[ot] = (o < 256) ? wv + (size_t)o * 256
             : (o < 288) ? wq + (size_t)(o - 256) * 256
                         : wk + (size_t)(o - 288) * 256;
  }

  f32x4 acc[5][4];
#pragma unroll
  for (int ot = 0; ot < 5; ++ot)
#pragma unroll
    for (int nt = 0; nt < 4; ++nt) acc[ot][nt] = f32x4{0.f, 0.f, 0.f, 0.f};

#pragma unroll
  for (int k = 0; k < 8; ++k) {
    u16x8 a[5], bfr[4];
#pragma unroll
    for (int ot = 0; ot < 5; ++ot) {
      const f32x4 w0 = *(const f32x4*)(wsrc[ot] + k * 32 + 8 * g);
      const f32x4 w1 = *(const f32x4*)(wsrc[ot] + k * 32 + 8 * g + 4);
      const u32x4 pw = {pk_bf16(w0.x, w0.y), pk_bf16(w0.z, w0.w),
                        pk_bf16(w1.x, w1.y), pk_bf16(w1.z, w1.w)};
      a[ot] = __builtin_bit_cast(u16x8, pw);
    }
#pragma unroll
    for (int nt = 0; nt < 4; ++nt)
      bfr[nt] = *(const u16x8*)(&xT[(r + 16 * nt) * 264 + k * 32 + g * 8]);
#pragma unroll
    for (int ot = 0; ot < 5; ++ot)
#pragma unroll
      for (int nt = 0; nt < 4; ++nt)
        acc[ot][nt] = mfma16(a[ot], bfr[nt], acc[ot][nt]);
  }

#pragma unroll
  for (int ot = 0; ot < 5; ++ot) {
    const int ob = o0 + ot * 16;
    if (ob < 256) {
      const f32x4 bs = *(const f32x4*)(bv + ob + 4 * g);
#pragma unroll
      for (int nt = 0; nt < 4; ++nt)
#pragma unroll
        for (int j = 0; j < 4; ++j) {
          const float vvv = acc[ot][nt][j] + bs[j];
          vbf[(size_t)(b * 256 + ob + 4 * g + j) * NN + n0 + r + 16 * nt] =
              (u16)(pk_bf16(vvv, 0.f) & 0xffffu);
        }
    } else {
      u16* dst;
      const float* bsrc;
      if (ob < 288) { dst = qT; bsrc = bq + (ob - 256); }
      else          { dst = kT; bsrc = bk + (ob - 288); }
      const f32x4 bs = *(const f32x4*)(bsrc + 4 * g);
      const int d0 = ((ob - 256) & 31) + 4 * g;
#pragma unroll
      for (int nt = 0; nt < 4; ++nt) {
        u32x2 pq;
        pq.x = pk_bf16(acc[ot][nt][0] + bs[0], acc[ot][nt][1] + bs[1]);
        pq.y = pk_bf16(acc[ot][nt][2] + bs[2], acc[ot][nt][3] + bs[3]);
        *(u32x2*)(dst + (size_t)(b * NN + n0 + r + 16 * nt) * 32 + d0) = pq;
      }
    }
  }
}

// ---------------------------------------------------------------------------
// Kernel 2: per-column softmax statistics (verified, byte-identical).
// ---------------------------------------------------------------------------
__global__ __launch_bounds__(256) void rowstat_kernel(
    const u16* __restrict__ qT, const u16* __restrict__ kT,
    float* __restrict__ Mx, float* __restrict__ invL) {
  const int lane = threadIdx.x & 63;
  const int wave = threadIdx.x >> 6;
  const int strip = blockIdx.x * 4 + wave;
  const int b  = strip >> 8;
  const int m0 = (strip & 255) * 16;
  const int r = lane & 15, g = lane >> 4;

  const u16x8 kB = *(const u16x8*)(kT + ((size_t)(b * NN + m0 + r)) * 32 + 8 * g);
  const u16* qbase = qT + ((size_t)(b * NN + r)) * 32 + 8 * g;

  float vmax = -3.0e38f, vsum = 0.f;
  for (int it = 0; it < 256; ++it) {
    const u16x8 qA = *(const u16x8*)(qbase + (size_t)it * 16 * 32);
    f32x4 s = mfma16(qA, kB, f32x4{0.f, 0.f, 0.f, 0.f});
    const float sm = fmaxf(fmaxf(s.x, s.y), fmaxf(s.z, s.w));
    const float nm = fmaxf(vmax, sm);
    vsum = vsum * exp2fast((vmax - nm) * L2E)
         + exp2fast((s.x - nm) * L2E) + exp2fast((s.y - nm) * L2E)
         + exp2fast((s.z - nm) * L2E) + exp2fast((s.w - nm) * L2E);
    vmax = nm;
  }
#pragma unroll
  for (int off = 16; off < 64; off <<= 1) {
    const float om = __shfl_xor(vmax, off);
    const float os = __shfl_xor(vsum, off);
    const float nm = fmaxf(vmax, om);
    vsum = vsum * exp2fast((vmax - nm) * L2E) + os * exp2fast((om - nm) * L2E);
    vmax = nm;
  }
  if (lane < 16) {
    Mx[b * NN + m0 + lane]   = vmax;
    invL[b * NN + m0 + lane] = 1.0f / vsum;
  }
}

// ---------------------------------------------------------------------------
// Kernel 3a: attention — ROUND-5 VERBATIM (verified).  Fallback if ws small.
// ---------------------------------------------------------------------------
__global__ __launch_bounds__(512, 2) void attn_kernel(
    const u16* __restrict__ qT, const u16* __restrict__ kT, const u16* __restrict__ vv,
    const float* __restrict__ Mx, const float* __restrict__ invL,
    const float* __restrict__ inp, const float* __restrict__ gptr,
    float* __restrict__ out) {
  __shared__ u32 q_lds[32 * 20];
  __shared__ u32 v_lds[32 * 20];

  const int tid  = threadIdx.x;
  const int lane = tid & 63;
  const int wave = tid >> 6;
  const int r = lane & 15, g = lane >> 4;

  const int bi   = blockIdx.x >> 5;
  const int rest = blockIdx.x & 31;
  const int cs   = rest >> 2;
  const int mg   = rest & 3;
  const int m0   = (mg * 8 + wave) * 128;
  const int c0   = cs * 32;
  const float gamma = gptr[0];

  u16x8 kB[8];
#pragma unroll
  for (int t = 0; t < 8; ++t)
    kB[t] = *(const u16x8*)(kT + ((size_t)(bi * NN + m0 + t * 16 + r)) * DD + 8 * g);
  float msc[8];
#pragma unroll
  for (int t = 0; t < 8; ++t) msc[t] = Mx[bi * NN + m0 + t * 16 + r] * L2E;

  f32x4 acc[2][8];
#pragma unroll
  for (int cb = 0; cb < 2; ++cb)
#pragma unroll
    for (int t = 0; t < 8; ++t) acc[cb][t] = f32x4{0.f, 0.f, 0.f, 0.f};

  const int srow = tid >> 4;
  const int sdw  = tid & 15;
  const u32* qsrc = (const u32*)(qT + ((size_t)(bi * NN + srow)) * DD) + sdw;
  const u32* vsrc = (const u32*)(vv + ((size_t)(bi * CC + c0 + srow)) * NN) + sdw;
  u32* qdst = q_lds + srow * 20 + sdw;
  u32* vdst = v_lds + srow * 20 + sdw;

  qdst[0] = qsrc[0];
  vdst[0] = vsrc[0];

  for (int i0 = 0; i0 < NN; i0 += 32) {
    __syncthreads();
    const bool more = (i0 + 32) < NN;
    u32 nq = 0, nv = 0;
    if (more) {
      nq = qsrc[(size_t)(i0 + 32) * (DD / 2)];
      nv = vsrc[(i0 + 32) >> 1];
    }

    const u16x8 qA0 = __builtin_bit_cast(u16x8, *(const u32x4*)(q_lds + r * 20 + 4 * g));
    const u16x8 qA1 = __builtin_bit_cast(u16x8, *(const u32x4*)(q_lds + (16 + r) * 20 + 4 * g));
    const u32x2 vl0 = *(const u32x2*)(v_lds + r * 20 + 2 * g);
    const u32x2 vh0 = *(const u32x2*)(v_lds + r * 20 + 2 * g + 8);
    const u32x2 vl1 = *(const u32x2*)(v_lds + (16 + r) * 20 + 2 * g);
    const u32x2 vh1 = *(const u32x2*)(v_lds + (16 + r) * 20 + 2 * g + 8);
    const u16x8 vA0 = __builtin_bit_cast(u16x8, u32x4{vl0.x, vl0.y, vh0.x, vh0.y});
    const u16x8 vA1 = __builtin_bit_cast(u16x8, u32x4{vl1.x, vl1.y, vh1.x, vh1.y});

#pragma unroll
    for (int t = 0; t < 8; ++t) {
      const f32x4 s0 = mfma16(qA0, kB[t], f32x4{0.f, 0.f, 0.f, 0.f});
      const f32x4 s1 = mfma16(qA1, kB[t], f32x4{0.f, 0.f, 0.f, 0.f});
      const float p0 = exp2fast(fmaf(s0.x, L2E, -msc[t]));
      const float p1 = exp2fast(fmaf(s0.y, L2E, -msc[t]));
      const float p2 = exp2fast(fmaf(s0.z, L2E, -msc[t]));
      const float p3 = exp2fast(fmaf(s0.w, L2E, -msc[t]));
      const float p4 = exp2fast(fmaf(s1.x, L2E, -msc[t]));
      const float p5 = exp2fast(fmaf(s1.y, L2E, -msc[t]));
      const float p6 = exp2fast(fmaf(s1.z, L2E, -msc[t]));
      const float p7 = exp2fast(fmaf(s1.w, L2E, -msc[t]));
      const u32x4 pb = {pk_bf16(p0, p1), pk_bf16(p2, p3), pk_bf16(p4, p5), pk_bf16(p6, p7)};
      const u16x8 PB = __builtin_bit_cast(u16x8, pb);
      acc[0][t] = mfma16(vA0, PB, acc[0][t]);
      acc[1][t] = mfma16(vA1, PB, acc[1][t]);
    }
    __syncthreads();
    if (more) { qdst[0] = nq; vdst[0] = nv; }
  }

#pragma unroll
  for (int t = 0; t < 8; ++t) {
    const float il = invL[bi * NN + m0 + t * 16 + r] * gamma;
#pragma unroll
    for (int cb = 0; cb < 2; ++cb) {
#pragma unroll
      for (int rr = 0; rr < 4; ++rr) {
        const int c = c0 + cb * 16 + g * 4 + rr;
        const size_t idx = ((size_t)(bi * CC + c)) * NN + m0 + t * 16 + r;
        out[idx] = acc[cb][t][rr] * il + inp[idx];
      }
    }
  }
}

// ---------------------------------------------------------------------------
// Kernel 3b: attention, c-strip 64 + i-half split.  Cursed core UNCHANGED
// from r5/r10: kB[8], msc[8], t<8 loop, PB construction, q staging, LDS row
// geometry, barrier loop.  Changes are only r10-proven classes (grid/decode/
// i-bounds/partial epilogue) + c-width doubling: vld 64 rows (r5 staging
// expression cloned at +32), vA[4], acc[4][8].  Halves total exp2/fmaf/cvt.
// Grid 256 = 2 halves x 8 b x 4 cs x 4 mg.
// ---------------------------------------------------------------------------
__global__ __launch_bounds__(512, 2) void attn_c64_kernel(
    const u16* __restrict__ qT, const u16* __restrict__ kT, const u16* __restrict__ vv,
    const float* __restrict__ Mx, const float* __restrict__ invL,
    const float* __restrict__ gptr, u16* __restrict__ pout) {
  __shared__ u32 q_lds[32 * 20];
  __shared__ u32 v_lds[64 * 20];

  const int tid  = threadIdx.x;
  const int lane = tid & 63;
  const int wave = tid >> 6;                 // 0..7
  const int r = lane & 15, g = lane >> 4;

  const int half   = blockIdx.x >> 7;        // 0,1: i-range half
  const int bindex = blockIdx.x & 127;
  const int ibase  = half << 11;             // 0 or 2048

  const int bi   = bindex >> 4;              // 8 batches
  const int rest = bindex & 15;
  const int cs   = rest >> 2;                // 0..3  c-strip (64 wide)
  const int mg   = rest & 3;                 // 0..3  m-group
  const int m0   = (mg * 8 + wave) * 128;    // r5 formula
  const int c0   = cs * 64;
  const float gamma = gptr[0];

  u16x8 kB[8];
#pragma unroll
  for (int t = 0; t < 8; ++t)
    kB[t] = *(const u16x8*)(kT + ((size_t)(bi * NN + m0 + t * 16 + r)) * DD + 8 * g);
  float msc[8];
#pragma unroll
  for (int t = 0; t < 8; ++t) msc[t] = Mx[bi * NN + m0 + t * 16 + r] * L2E;

  f32x4 acc[4][8];
#pragma unroll
  for (int ct = 0; ct < 4; ++ct)
#pragma unroll
    for (int t = 0; t < 8; ++t) acc[ct][t] = f32x4{0.f, 0.f, 0.f, 0.f};

  const int srow = tid >> 4;   // 0..31
  const int sdw  = tid & 15;   // dword within row
  const u32* qsrc  = (const u32*)(qT + ((size_t)(bi * NN + srow)) * DD) + sdw;
  const u32* vsrc0 = (const u32*)(vv + ((size_t)(bi * CC + c0 + srow)) * NN) + sdw;
  const u32* vsrc1 = (const u32*)(vv + ((size_t)(bi * CC + c0 + 32 + srow)) * NN) + sdw;
  u32* qdst  = q_lds + srow * 20 + sdw;
  u32* vdst0 = v_lds + srow * 20 + sdw;
  u32* vdst1 = v_lds + (32 + srow) * 20 + sdw;

  qdst[0]  = qsrc[(size_t)ibase * (DD / 2)];  // stage first tile of this half
  vdst0[0] = vsrc0[ibase >> 1];
  vdst1[0] = vsrc1[ibase >> 1];

  for (int i0 = ibase; i0 < ibase + 2048; i0 += 32) {
    __syncthreads();                          // staged tile visible
    const bool more = (i0 + 32) < (ibase + 2048);
    u32 nq = 0, nv0 = 0, nv1 = 0;
    if (more) {
      nq  = qsrc[(size_t)(i0 + 32) * (DD / 2)];
      nv0 = vsrc0[(i0 + 32) >> 1];
      nv1 = vsrc1[(i0 + 32) >> 1];
    }

    const u16x8 qA0 = __builtin_bit_cast(u16x8, *(const u32x4*)(q_lds + r * 20 + 4 * g));
    const u16x8 qA1 = __builtin_bit_cast(u16x8, *(const u32x4*)(q_lds + (16 + r) * 20 + 4 * g));

    u16x8 vA[4];
#pragma unroll
    for (int ct = 0; ct < 4; ++ct) {
      const u32* vr = v_lds + (ct * 16 + r) * 20;
      const u32x2 vl = *(const u32x2*)(vr + 2 * g);
      const u32x2 vh = *(const u32x2*)(vr + 2 * g + 8);
      vA[ct] = __builtin_bit_cast(u16x8, u32x4{vl.x, vl.y, vh.x, vh.y});
    }

#pragma unroll
    for (int t = 0; t < 8; ++t) {
      const f32x4 s0 = mfma16(qA0, kB[t], f32x4{0.f, 0.f, 0.f, 0.f});
      const f32x4 s1 = mfma16(qA1, kB[t], f32x4{0.f, 0.f, 0.f, 0.f});
      const float p0 = exp2fast(fmaf(s0.x, L2E, -msc[t]));
      const float p1 = exp2fast(fmaf(s0.y, L2E, -msc[t]));
      const float p2 = exp2fast(fmaf(s0.z, L2E, -msc[t]));
      const float p3 = exp2fast(fmaf(s0.w, L2E, -msc[t]));
      const float p4 = exp2fast(fmaf(s1.x, L2E, -msc[t]));
      const float p5 = exp2fast(fmaf(s1.y, L2E, -msc[t]));
      const float p6 = exp2fast(fmaf(s1.z, L2E, -msc[t]));
      const float p7 = exp2fast(fmaf(s1.w, L2E, -msc[t]));
      const u32x4 pb = {pk_bf16(p0, p1), pk_bf16(p2, p3), pk_bf16(p4, p5), pk_bf16(p6, p7)};
      const u16x8 PB = __builtin_bit_cast(u16x8, pb);
#pragma unroll
      for (int ct = 0; ct < 4; ++ct)
        acc[ct][t] = mfma16(vA[ct], PB, acc[ct][t]);
    }
    __syncthreads();                          // all reads done before overwrite
    if (more) { qdst[0] = nq; vdst0[0] = nv0; vdst1[0] = nv1; }
  }

  // epilogue: partial = gamma * invL * O_half, stored bf16 (r10-proven form)
  u16* pd = pout + (size_t)half * (8UL * 256 * 4096);
#pragma unroll
  for (int t = 0; t < 8; ++t) {
    const float il = invL[bi * NN + m0 + t * 16 + r] * gamma;
#pragma unroll
    for (int ct = 0; ct < 4; ++ct) {
#pragma unroll
      for (int rr = 0; rr < 4; ++rr) {
        const int c = c0 + ct * 16 + g * 4 + rr;
        const size_t idx = ((size_t)(bi * CC + c)) * NN + m0 + t * 16 + r;
        pd[idx] = (u16)(pk_bf16(acc[ct][t][rr] * il, 0.f) & 0xffffu);
      }
    }
  }
}

// ---------------------------------------------------------------------------
// Kernel 4: combine — out = p0 + p1 + inp (r10 verbatim, verified).
// ---------------------------------------------------------------------------
__global__ __launch_bounds__(256) void combine_kernel(
    const u16* __restrict__ p, const float* __restrict__ inp,
    float* __restrict__ out) {
  const size_t HALF = 8UL * 256 * 4096;
  const size_t stride = (size_t)gridDim.x * 256 * 4;
  for (size_t i = ((size_t)blockIdx.x * 256 + threadIdx.x) * 4; i < HALF; i += stride) {
    const u32x2 a = *(const u32x2*)(p + i);
    const u32x2 b = *(const u32x2*)(p + HALF + i);
    const f32x4 x = *(const f32x4*)(inp + i);
    f32x4 o;
    o.x = x.x + lo16(a.x) + lo16(b.x);
    o.y = x.y + hi16(a.x) + hi16(b.x);
    o.z = x.z + lo16(a.y) + lo16(b.y);
    o.w = x.w + hi16(a.y) + hi16(b.y);
    *(f32x4*)(out + i) = o;
  }
}

// ---------------------------------------------------------------------------
// d_ws layout:
//   [0,2MB) qT | [2,4MB) kT | [4,20MB) vbf | [20MB,+128KB) Mx | [+,+256KB) iL
//   [20.25MB, +33.6MB) bf16 partials (ws >= 54MB proven by r10's branch).
//   Fallback on small ws: r5 single-kernel attn (deterministic branch).
// ---------------------------------------------------------------------------
extern "C" void kernel_launch(void* const* d_in, const int* in_sizes, int n_in,
                              void* d_out, int out_size, void* d_ws, size_t ws_size,
                              hipStream_t stream) {
  const float* in  = (const float*)d_in[0];
  const float* wq  = (const float*)d_in[1];
  const float* bq  = (const float*)d_in[2];
  const float* wk  = (const float*)d_in[3];
  const float* bk  = (const float*)d_in[4];
  const float* wv  = (const float*)d_in[5];
  const float* bv  = (const float*)d_in[6];
  const float* gam = (const float*)d_in[7];
  float* out = (float*)d_out;

  char* ws = (char*)d_ws;
  u16* qT   = (u16*)(ws);
  u16* kT   = (u16*)(ws + (2u << 20));
  u16* vbf  = (u16*)(ws + (4u << 20));
  float* Mx = (float*)(ws + (20u << 20));
  float* iL = (float*)(ws + (20u << 20) + (1u << 17));
  u16* pout = (u16*)(ws + (20u << 20) + (1u << 18));

  const size_t need = (20u << 20) + (1u << 18) + 2 * (8UL * 256 * 4096) * 2;

  proj_kernel<<<512, 256, 0, stream>>>(in, wq, wk, wv, bq, bk, bv, qT, kT, vbf);
  rowstat_kernel<<<512, 256, 0, stream>>>(qT, kT, Mx, iL);
  if (ws_size >= need) {
    attn_c64_kernel<<<256, 512, 0, stream>>>(qT, kT, vbf, Mx, iL, gam, pout);
    combine_kernel<<<2048, 256, 0, stream>>>(pout, in, out);
  } else {
    attn_kernel<<<256, 512, 0, stream>>>(qT, kT, vbf, Mx, iL, in, gam, out);
  }
}